// Round 9
// baseline (13711.186 us; speedup 1.0000x reference)
//
#include <hip/hip_runtime.h>
#include <hip/hip_bf16.h>
#include <math.h>

// RSSM scan — numpy-realization f32 (PASSING cell, frozen numerics):
//   GEMM: OpenBLAS replica — K panels of 384, per-output single-acc k-ascending
//   fmaf chain per panel, panels folded ascending by consumer. Reductions:
//   numpy pairwise replica (frozen wave tree). CR transcendentals via f64.
// r9: 128x128/8x8 GEMM (2 FLOP/LDS-byte) for GX/GH/q1/prior, GH(t+1) merged
// into q1(t) launch (off critical path), 64x64/8x4 for pre/q2, elementwise
// transcendentals spread over 256 thr with wave0 frozen reduction.

struct GArg {
  const float* A0; int lda0;
  const float* A1; int lda1;
  int kSplit;
  const float* W; int ldw;
  float* C; int N; int K;             // panel s written at C + s*256*N
};

__device__ __forceinline__ float exp_cr(float x)  { return (float)exp((double)x); }
__device__ __forceinline__ float log_cr(float x)  { return (float)log((double)x); }
__device__ __forceinline__ float tanh_cr(float x) { return (float)tanh((double)x); }
__device__ __forceinline__ float sigmoid_cr(float x) {
  float e = exp_cr(-x);
  float d = __fadd_rn(1.0f, e);
  return __fdiv_rn(1.0f, d);
}

// ---- 64x64 tile, 128 threads, 8x4 per thread (pre / q2) ----
__global__ __launch_bounds__(128) void gemm64_k(GArg g0, GArg g1, int zSplit, int tpp) {
  int z = blockIdx.z;
  GArg G; int s;
  if (z < zSplit) { G = g0; s = z; } else { G = g1; s = z - zSplit; }
  int n0 = blockIdx.x * 64;
  if (n0 >= G.N) return;
  int m0 = blockIdx.y * 64;

  __shared__ float As[2][16][68];   // rows 272B (16B-aligned); reads 2-way max
  __shared__ float Bs[2][16][68];

  int tid = threadIdx.x;
  int tx = tid & 15, ty = tid >> 4;         // staging: k-col, 8-row group (0..7)
  int w = tid >> 6, lane = tid & 63;
  int rg = lane >> 3;                       // rows rg*8..+7
  int cg = (lane & 7) + w * 8;              // cols cg*4..+3

  float acc[8][4];
  #pragma unroll
  for (int j = 0; j < 8; ++j)
    #pragma unroll
    for (int i = 0; i < 4; ++i) acc[j][i] = 0.0f;

  int nt = (G.K + 15) >> 4;
  int t0 = s * tpp, t1 = min(nt, t0 + tpp);

  float a[8], wv[8];
  auto stage_load = [&](int kt) {
    int k = kt * 16 + tx;
    if (k < G.K) {
      if (k < G.kSplit) {
        const float* Ap = G.A0 + (size_t)(m0 + ty * 8) * G.lda0 + k;
        #pragma unroll
        for (int i = 0; i < 8; ++i) a[i] = Ap[(size_t)i * G.lda0];
      } else {
        const float* Ap = G.A1 + (size_t)(m0 + ty * 8) * G.lda1 + (k - G.kSplit);
        #pragma unroll
        for (int i = 0; i < 8; ++i) a[i] = Ap[(size_t)i * G.lda1];
      }
      const float* Wp = G.W + (size_t)(n0 + ty * 8) * G.ldw + k;
      #pragma unroll
      for (int i = 0; i < 8; ++i) wv[i] = Wp[(size_t)i * G.ldw];
    } else {
      #pragma unroll
      for (int i = 0; i < 8; ++i) { a[i] = 0.0f; wv[i] = 0.0f; }
    }
  };
  auto stage_write = [&](int b) {
    *(float4*)&As[b][tx][ty * 8]     = make_float4(a[0], a[1], a[2], a[3]);
    *(float4*)&As[b][tx][ty * 8 + 4] = make_float4(a[4], a[5], a[6], a[7]);
    *(float4*)&Bs[b][tx][ty * 8]     = make_float4(wv[0], wv[1], wv[2], wv[3]);
    *(float4*)&Bs[b][tx][ty * 8 + 4] = make_float4(wv[4], wv[5], wv[6], wv[7]);
  };
  auto compute = [&](int b) {
    #pragma unroll
    for (int kk = 0; kk < 16; ++kk) {
      float4 a0 = *(const float4*)&As[b][kk][rg * 8];
      float4 a1 = *(const float4*)&As[b][kk][rg * 8 + 4];
      float4 bb = *(const float4*)&Bs[b][kk][cg * 4];
      float ar[8] = {a0.x, a0.y, a0.z, a0.w, a1.x, a1.y, a1.z, a1.w};
      float br[4] = {bb.x, bb.y, bb.z, bb.w};
      #pragma unroll
      for (int j = 0; j < 8; ++j)
        #pragma unroll
        for (int i = 0; i < 4; ++i)
          acc[j][i] = fmaf(ar[j], br[i], acc[j][i]);   // k-ascending chain
    }
  };

  stage_load(t0); stage_write(0); __syncthreads();
  int cur = 0;
  for (int kt = t0; kt < t1; ++kt) {
    if (kt + 1 < t1) {
      stage_load(kt + 1);
      compute(cur);
      stage_write(cur ^ 1);
      __syncthreads();
      cur ^= 1;
    } else compute(cur);
  }

  float* Cp = G.C + (size_t)s * 256 * G.N;
  #pragma unroll
  for (int j = 0; j < 8; ++j)
    *(float4*)&Cp[(size_t)(m0 + rg * 8 + j) * G.N + n0 + cg * 4] =
      make_float4(acc[j][0], acc[j][1], acc[j][2], acc[j][3]);
}

// ---- 128x128 tile, 256 threads, 8x8 per thread (GX/GH/q1/prior) ----
__global__ __launch_bounds__(256) void gemm128_k(GArg g0, GArg g1, int zSplit, int tpp) {
  int z = blockIdx.z;
  GArg G; int s;
  if (z < zSplit) { G = g0; s = z; } else { G = g1; s = z - zSplit; }
  int n0 = blockIdx.x * 128;
  if (n0 >= G.N) return;
  int m0 = blockIdx.y * 128;

  __shared__ float As[2][16][132];  // rows 528B (16B-aligned); reads 2-way max
  __shared__ float Bs[2][16][132];

  int tid = threadIdx.x;
  int tx = tid & 15, ty = tid >> 4;          // staging: k-col, 8-row group (0..15)
  int w = tid >> 6, lane = tid & 63;
  int orow = (w >> 1) * 64 + (lane >> 3) * 8;   // wave quadrant + 8-lane split
  int ocol = (w & 1) * 64 + (lane & 7) * 8;

  float acc[8][8];
  #pragma unroll
  for (int j = 0; j < 8; ++j)
    #pragma unroll
    for (int i = 0; i < 8; ++i) acc[j][i] = 0.0f;

  int nt = (G.K + 15) >> 4;
  int t0 = s * tpp, t1 = min(nt, t0 + tpp);

  float a[8], wv[8];
  auto stage_load = [&](int kt) {
    int k = kt * 16 + tx;
    if (k < G.K) {
      if (k < G.kSplit) {
        const float* Ap = G.A0 + (size_t)(m0 + ty * 8) * G.lda0 + k;
        #pragma unroll
        for (int i = 0; i < 8; ++i) a[i] = Ap[(size_t)i * G.lda0];
      } else {
        const float* Ap = G.A1 + (size_t)(m0 + ty * 8) * G.lda1 + (k - G.kSplit);
        #pragma unroll
        for (int i = 0; i < 8; ++i) a[i] = Ap[(size_t)i * G.lda1];
      }
      const float* Wp = G.W + (size_t)(n0 + ty * 8) * G.ldw + k;
      #pragma unroll
      for (int i = 0; i < 8; ++i) wv[i] = Wp[(size_t)i * G.ldw];
    } else {
      #pragma unroll
      for (int i = 0; i < 8; ++i) { a[i] = 0.0f; wv[i] = 0.0f; }
    }
  };
  auto stage_write = [&](int b) {
    *(float4*)&As[b][tx][ty * 8]     = make_float4(a[0], a[1], a[2], a[3]);
    *(float4*)&As[b][tx][ty * 8 + 4] = make_float4(a[4], a[5], a[6], a[7]);
    *(float4*)&Bs[b][tx][ty * 8]     = make_float4(wv[0], wv[1], wv[2], wv[3]);
    *(float4*)&Bs[b][tx][ty * 8 + 4] = make_float4(wv[4], wv[5], wv[6], wv[7]);
  };
  auto compute = [&](int b) {
    #pragma unroll
    for (int kk = 0; kk < 16; ++kk) {
      float4 a0 = *(const float4*)&As[b][kk][orow];
      float4 a1 = *(const float4*)&As[b][kk][orow + 4];
      float4 b0 = *(const float4*)&Bs[b][kk][ocol];
      float4 b1 = *(const float4*)&Bs[b][kk][ocol + 4];
      float ar[8] = {a0.x, a0.y, a0.z, a0.w, a1.x, a1.y, a1.z, a1.w};
      float br[8] = {b0.x, b0.y, b0.z, b0.w, b1.x, b1.y, b1.z, b1.w};
      #pragma unroll
      for (int j = 0; j < 8; ++j)
        #pragma unroll
        for (int i = 0; i < 8; ++i)
          acc[j][i] = fmaf(ar[j], br[i], acc[j][i]);   // k-ascending chain
    }
  };

  stage_load(t0); stage_write(0); __syncthreads();
  int cur = 0;
  for (int kt = t0; kt < t1; ++kt) {
    if (kt + 1 < t1) {
      stage_load(kt + 1);
      compute(cur);
      stage_write(cur ^ 1);
      __syncthreads();
      cur ^= 1;
    } else compute(cur);
  }

  float* Cp = G.C + (size_t)s * 256 * G.N;
  #pragma unroll
  for (int j = 0; j < 8; ++j) {
    *(float4*)&Cp[(size_t)(m0 + orow + j) * G.N + n0 + ocol] =
      make_float4(acc[j][0], acc[j][1], acc[j][2], acc[j][3]);
    *(float4*)&Cp[(size_t)(m0 + orow + j) * G.N + n0 + ocol + 4] =
      make_float4(acc[j][4], acc[j][5], acc[j][6], acc[j][7]);
  }
}

// ---- LN + SiLU, 256 thr/row; wave0 replays FROZEN pairwise reduction ----
__global__ __launch_bounds__(256) void lnsilu256_k(
  const float* Y, int S, const float* bias, const float* gg, const float* be, float* O)
{
  __shared__ float xs[64][20];
  __shared__ float stats[2];
  int row = blockIdx.x, tid = threadIdx.x;
  int cl = tid & 63, iq = tid >> 6;
  int kb = cl >> 3, j = cl & 7;

  float xv[4];
  #pragma unroll
  for (int q = 0; q < 4; ++q) {
    int i = iq * 4 + q;
    int n = kb * 128 + 8 * i + j;
    size_t idx = (size_t)row * 1024 + n;
    float x = Y[idx];
    for (int ss = 1; ss < S; ++ss) x = __fadd_rn(x, Y[(size_t)ss * 262144 + idx]);
    x = __fadd_rn(x, bias[n]);
    xv[q] = x;
    xs[cl][i] = x;
  }
  __syncthreads();
  if (tid < 64) {
    float r = xs[cl][0];
    #pragma unroll
    for (int i = 1; i < 16; ++i) r = __fadd_rn(r, xs[cl][i]);
    r = __fadd_rn(r, __shfl_xor(r, 1));
    r = __fadd_rn(r, __shfl_xor(r, 2));
    r = __fadd_rn(r, __shfl_xor(r, 4));
    r = __fadd_rn(r, __shfl_xor(r, 8));
    r = __fadd_rn(r, __shfl_xor(r, 16));
    r = __fadd_rn(r, __shfl_xor(r, 32));
    float mean = __fmul_rn(r, 0.0009765625f);
    float d0 = __fsub_rn(xs[cl][0], mean);
    float r2 = __fmul_rn(d0, d0);
    #pragma unroll
    for (int i = 1; i < 16; ++i) {
      float d = __fsub_rn(xs[cl][i], mean);
      r2 = __fadd_rn(r2, __fmul_rn(d, d));
    }
    r2 = __fadd_rn(r2, __shfl_xor(r2, 1));
    r2 = __fadd_rn(r2, __shfl_xor(r2, 2));
    r2 = __fadd_rn(r2, __shfl_xor(r2, 4));
    r2 = __fadd_rn(r2, __shfl_xor(r2, 8));
    r2 = __fadd_rn(r2, __shfl_xor(r2, 16));
    r2 = __fadd_rn(r2, __shfl_xor(r2, 32));
    float var = __fmul_rn(r2, 0.0009765625f);
    float sdv = __fsqrt_rn(__fadd_rn(var, (float)1e-5));
    if (cl == 0) { stats[0] = mean; stats[1] = __fdiv_rn(1.0f, sdv); }
  }
  __syncthreads();
  float mean = stats[0], rstd = stats[1];
  #pragma unroll
  for (int q = 0; q < 4; ++q) {
    int i = iq * 4 + q;
    int n = kb * 128 + 8 * i + j;
    float d = __fsub_rn(xv[q], mean);
    float t = __fmul_rn(__fmul_rn(d, rstd), gg[n]);
    t = __fadd_rn(t, be[n]);
    O[(size_t)row * 1024 + n] = __fmul_rn(t, sigmoid_cr(t));   // silu
  }
}

// ---- GRU combine + LN, 256 thr/row; wave0 frozen reduction ----
__global__ __launch_bounds__(256) void gru256_k(
  const float* GX, const float* GH, float* H,
  const float* b_ih, const float* b_hh, const float* g_gn, const float* b_gn,
  float* out, int t)
{
  __shared__ float xs[64][20];
  __shared__ float stats[2];
  int row = blockIdx.x, tid = threadIdx.x;
  int cl = tid & 63, iq = tid >> 6;
  int kb = cl >> 3, j = cl & 7;

  float hv[4];
  #pragma unroll
  for (int q = 0; q < 4; ++q) {
    int i = iq * 4 + q;
    int n = kb * 128 + 8 * i + j;
    size_t i0 = (size_t)row * 3072 + n;
    #define FOLD3(P, off) __fadd_rn(__fadd_rn((P)[off], (P)[786432 + (off)]), (P)[1572864 + (off)])
    float xr = __fadd_rn(FOLD3(GX, i0),        b_ih[n]);
    float xu = __fadd_rn(FOLD3(GX, i0 + 1024), b_ih[n + 1024]);
    float xn = __fadd_rn(FOLD3(GX, i0 + 2048), b_ih[n + 2048]);
    float hr = __fadd_rn(FOLD3(GH, i0),        b_hh[n]);
    float hu = __fadd_rn(FOLD3(GH, i0 + 1024), b_hh[n + 1024]);
    float hn = __fadd_rn(FOLD3(GH, i0 + 2048), b_hh[n + 2048]);
    #undef FOLD3
    float r = sigmoid_cr(__fadd_rn(xr, hr));
    float u = sigmoid_cr(__fadd_rn(xu, hu));
    float nn = tanh_cr(__fadd_rn(xn, __fmul_rn(r, hn)));
    float h2 = __fadd_rn(__fmul_rn(__fsub_rn(1.0f, u), nn),
                         __fmul_rn(u, H[(size_t)row * 1024 + n]));
    hv[q] = h2;
    xs[cl][i] = h2;
  }
  __syncthreads();
  if (tid < 64) {
    float r = xs[cl][0];
    #pragma unroll
    for (int i = 1; i < 16; ++i) r = __fadd_rn(r, xs[cl][i]);
    r = __fadd_rn(r, __shfl_xor(r, 1));
    r = __fadd_rn(r, __shfl_xor(r, 2));
    r = __fadd_rn(r, __shfl_xor(r, 4));
    r = __fadd_rn(r, __shfl_xor(r, 8));
    r = __fadd_rn(r, __shfl_xor(r, 16));
    r = __fadd_rn(r, __shfl_xor(r, 32));
    float mean = __fmul_rn(r, 0.0009765625f);
    float d0 = __fsub_rn(xs[cl][0], mean);
    float r2 = __fmul_rn(d0, d0);
    #pragma unroll
    for (int i = 1; i < 16; ++i) {
      float d = __fsub_rn(xs[cl][i], mean);
      r2 = __fadd_rn(r2, __fmul_rn(d, d));
    }
    r2 = __fadd_rn(r2, __shfl_xor(r2, 1));
    r2 = __fadd_rn(r2, __shfl_xor(r2, 2));
    r2 = __fadd_rn(r2, __shfl_xor(r2, 4));
    r2 = __fadd_rn(r2, __shfl_xor(r2, 8));
    r2 = __fadd_rn(r2, __shfl_xor(r2, 16));
    r2 = __fadd_rn(r2, __shfl_xor(r2, 32));
    float var = __fmul_rn(r2, 0.0009765625f);
    float sdv = __fsqrt_rn(__fadd_rn(var, (float)1e-5));
    if (cl == 0) { stats[0] = mean; stats[1] = __fdiv_rn(1.0f, sdv); }
  }
  __syncthreads();
  float mean = stats[0], rstd = stats[1];
  #pragma unroll
  for (int q = 0; q < 4; ++q) {
    int i = iq * 4 + q;
    int n = kb * 128 + 8 * i + j;
    float d = __fsub_rn(hv[q], mean);
    float h3 = __fadd_rn(__fmul_rn(__fmul_rn(d, rstd), g_gn[n]), b_gn[n]);
    H[(size_t)row * 1024 + n] = h3;
    out[((size_t)row * 64 + t) * 1024 + n] = h3;
  }
}

// ---- posterior softmax+unimix+gumbel argmax (FROZEN); qp/zs, z-carry ----
__global__ __launch_bounds__(256) void sample_post_k(
  const float* Yq, const float* bq2, const float* u_post, const float* actions,
  float* XZ, float* out, int t)
{
  const size_t NOUT = 16777216ull;
  int b = blockIdx.x, tid = threadIdx.x;
  int d = tid >> 3, lane = tid & 7;
  const float C0 = (float)(1.0 - 0.01);
  const float C1 = (float)(0.01 / 32.0);

  float lg[4];
  #pragma unroll
  for (int i = 0; i < 4; ++i) {
    int col = d * 32 + lane + 8 * i;
    size_t idx = (size_t)b * 1024 + col;
    float x = __fadd_rn(__fadd_rn(Yq[idx], Yq[262144 + idx]), Yq[524288 + idx]);
    lg[i] = __fadd_rn(x, bq2[col]);
  }
  float mx = fmaxf(fmaxf(lg[0], lg[1]), fmaxf(lg[2], lg[3]));
  for (int off = 4; off; off >>= 1) mx = fmaxf(mx, __shfl_xor(mx, off, 8));

  float e[4];
  #pragma unroll
  for (int i = 0; i < 4; ++i) e[i] = exp_cr(__fsub_rn(lg[i], mx));
  float ssum = e[0];
  ssum = __fadd_rn(ssum, e[1]);
  ssum = __fadd_rn(ssum, e[2]);
  ssum = __fadd_rn(ssum, e[3]);
  ssum = __fadd_rn(ssum, __shfl_xor(ssum, 1, 8));
  ssum = __fadd_rn(ssum, __shfl_xor(ssum, 2, 8));
  ssum = __fadd_rn(ssum, __shfl_xor(ssum, 4, 8));

  float p[4];
  #pragma unroll
  for (int i = 0; i < 4; ++i) {
    float pr = __fdiv_rn(e[i], ssum);
    p[i] = __fadd_rn(__fmul_rn(C0, pr), C1);
  }

  size_t ob = ((size_t)b * 64 + t) * 1024;
  float bv = -3.4e38f; int bc = 33;
  #pragma unroll
  for (int i = 0; i < 4; ++i) {
    int c = lane + 8 * i, col = d * 32 + c;
    out[3 * NOUT + ob + col] = p[i];
    float uu = u_post[((size_t)t * 256 + b) * 1024 + col];
    float l1 = log_cr(uu);
    float v1 = -l1;
    float l2 = log_cr(v1);
    float gu = -l2;
    float lp = log_cr(p[i]);
    float val = __fadd_rn(lp, gu);
    if (val > bv) { bv = val; bc = c; }
  }
  for (int off = 4; off; off >>= 1) {
    float ov = __shfl_xor(bv, off, 8);
    int   oc = __shfl_xor(bc, off, 8);
    if (ov > bv || (ov == bv && oc < bc)) { bv = ov; bc = oc; }
  }
  #pragma unroll
  for (int i = 0; i < 4; ++i) {
    int c = lane + 8 * i, col = d * 32 + c;
    float zv = 0.0f;
    if (c == bc) zv = __fsub_rn(__fadd_rn(1.0f, p[i]), p[i]);
    out[NOUT + ob + col] = zv;
    XZ[(size_t)b * 1040 + col] = zv;
  }
  if (tid < 6 && (t + 1) < 64)
    XZ[(size_t)b * 1040 + 1024 + tid] = actions[((size_t)b * 64 + (t + 1)) * 6 + tid];
}

// ---- prior softmax+unimix, in-place on pp region (value-safe) ----
__global__ __launch_bounds__(256) void prior_soft_k(float* pp, const float* bp2)
{
  int r = blockIdx.x, tid = threadIdx.x;
  int d = tid >> 3, lane = tid & 7;
  const float C0 = (float)(1.0 - 0.01);
  const float C1 = (float)(0.01 / 32.0);
  float* rowp = pp + (size_t)r * 1024;

  float lg[4];
  #pragma unroll
  for (int i = 0; i < 4; ++i) {
    int col = d * 32 + lane + 8 * i;
    lg[i] = __fadd_rn(rowp[col], bp2[col]);
  }
  float mx = fmaxf(fmaxf(lg[0], lg[1]), fmaxf(lg[2], lg[3]));
  for (int off = 4; off; off >>= 1) mx = fmaxf(mx, __shfl_xor(mx, off, 8));
  float e[4];
  #pragma unroll
  for (int i = 0; i < 4; ++i) e[i] = exp_cr(__fsub_rn(lg[i], mx));
  float ssum = e[0];
  ssum = __fadd_rn(ssum, e[1]);
  ssum = __fadd_rn(ssum, e[2]);
  ssum = __fadd_rn(ssum, e[3]);
  ssum = __fadd_rn(ssum, __shfl_xor(ssum, 1, 8));
  ssum = __fadd_rn(ssum, __shfl_xor(ssum, 2, 8));
  ssum = __fadd_rn(ssum, __shfl_xor(ssum, 4, 8));
  #pragma unroll
  for (int i = 0; i < 4; ++i) {
    int col = d * 32 + lane + 8 * i;
    float pr = __fdiv_rn(e[i], ssum);
    rowp[col] = __fadd_rn(__fmul_rn(C0, pr), C1);
  }
}

__global__ __launch_bounds__(256) void init_k(const float* h_init, const float* z_init,
                                              const float* actions, float* H, float* XZ)
{
  int b = blockIdx.x, tid = threadIdx.x;
  #pragma unroll
  for (int j = 0; j < 4; ++j) {
    int n = tid + j * 256;
    H [(size_t)b * 1024 + n] = h_init[(size_t)b * 1024 + n];
    XZ[(size_t)b * 1040 + n] = z_init[(size_t)b * 1024 + n];
  }
  if (tid < 6) XZ[(size_t)b * 1040 + 1024 + tid] = actions[(size_t)b * 64 * 6 + tid];
}

extern "C" void kernel_launch(void* const* d_in, const int* in_sizes, int n_in,
                              void* d_out, int out_size, void* d_ws, size_t ws_size,
                              hipStream_t stream)
{
  const float* embeds  = (const float*)d_in[0];
  const float* actions = (const float*)d_in[1];
  const float* h_init  = (const float*)d_in[2];
  const float* z_init  = (const float*)d_in[3];
  const float* W_pre   = (const float*)d_in[4];
  const float* b_pre   = (const float*)d_in[5];
  const float* g_pre   = (const float*)d_in[6];
  const float* be_pre  = (const float*)d_in[7];
  const float* W_ih    = (const float*)d_in[8];
  const float* W_hh    = (const float*)d_in[9];
  const float* b_ih    = (const float*)d_in[10];
  const float* b_hh    = (const float*)d_in[11];
  const float* g_gn    = (const float*)d_in[12];
  const float* b_gn    = (const float*)d_in[13];
  const float* Wp1     = (const float*)d_in[14];
  const float* bp1     = (const float*)d_in[15];
  const float* gp      = (const float*)d_in[16];
  const float* bpn     = (const float*)d_in[17];
  const float* Wp2     = (const float*)d_in[18];
  const float* bp2     = (const float*)d_in[19];
  const float* Wq1     = (const float*)d_in[20];
  const float* bq1     = (const float*)d_in[21];
  const float* gq      = (const float*)d_in[22];
  const float* bqn     = (const float*)d_in[23];
  const float* Wq2     = (const float*)d_in[24];
  const float* bq2     = (const float*)d_in[25];
  // d_in[26] = u_prior: unused
  const float* u_post  = (const float*)d_in[27];
  float* out           = (float*)d_out;
  const size_t NOUT = 16777216ull;

  // workspace: 8,392,704 floats = 33.57 MB (lifetime-audited aliases)
  float* W0   = (float*)d_ws;
  float* H    = W0;                    // 262144
  float* XZ   = W0 + 262144;           // 266240 (row stride 1040)
  float* PREY = W0 + 528384;           // 786432 (3 panels)
  float* Q1A  = PREY;                  // 262144 alias: dead before pre(t+1)
  float* GX   = W0 + 1314816;          // 2359296 (3 panels)
  float* GH   = W0 + 3674112;          // 2359296 (3 panels; lives across step)
  float* YQ   = W0 + 6033408;          // 1572864 (6 panels)
  float* YQ2  = W0 + 7606272;          // 786432 (3 panels)
  float* XPRE = YQ2;                   // 262144 alias: dead before q2(t+1)
  float* Y1c  = GX;                    // post-loop prior chunk (4096x1024)

  hipLaunchKernelGGL(init_k, dim3(256), dim3(256), 0, stream, h_init, z_init, actions, H, XZ);

  // prefix: pre(0) -> ln(0) -> GX(0)+GH(0)
  GArg pre0{XZ, 1040, XZ, 1040, 1030, W_pre, 1030, PREY, 1024, 1030};
  hipLaunchKernelGGL(gemm64_k, dim3(16, 4, 3), dim3(128), 0, stream, pre0, pre0, 3, 24);
  hipLaunchKernelGGL(lnsilu256_k, dim3(256), dim3(256), 0, stream,
                     PREY, 3, b_pre, g_pre, be_pre, XPRE);
  {
    GArg gx{XPRE, 1024, XPRE, 1024, 1024, W_ih, 1024, GX, 3072, 1024};
    GArg gh{H,    1024, H,    1024, 1024, W_hh, 1024, GH, 3072, 1024};
    hipLaunchKernelGGL(gemm128_k, dim3(24, 2, 6), dim3(256), 0, stream, gx, gh, 3, 24);
  }

  for (int t = 0; t < 64; ++t) {
    // gru: fold3(GX)+fold3(GH) -> H, hs
    hipLaunchKernelGGL(gru256_k, dim3(256), dim3(256), 0, stream,
                       GX, GH, H, b_ih, b_hh, g_gn, b_gn, out, t);
    // q1(t) [+ GH(t+1) off critical path]
    GArg q1{H, 1024, embeds + (size_t)t * 1024, 65536, 1024, Wq1, 2048, YQ, 1024, 2048};
    GArg gh{H, 1024, H, 1024, 1024, W_hh, 1024, GH, 3072, 1024};
    if (t < 63)
      hipLaunchKernelGGL(gemm128_k, dim3(24, 2, 9), dim3(256), 0, stream, q1, gh, 6, 24);
    else
      hipLaunchKernelGGL(gemm128_k, dim3(8, 2, 6), dim3(256), 0, stream, q1, q1, 6, 24);
    // lnq -> Q1A
    hipLaunchKernelGGL(lnsilu256_k, dim3(256), dim3(256), 0, stream,
                       YQ, 6, bq1, gq, bqn, Q1A);
    // q2 -> YQ2
    GArg q2{Q1A, 1024, Q1A, 1024, 1024, Wq2, 1024, YQ2, 1024, 1024};
    hipLaunchKernelGGL(gemm64_k, dim3(16, 4, 3), dim3(128), 0, stream, q2, q2, 3, 24);
    // posterior sample -> qp/zs, next [z|a]
    hipLaunchKernelGGL(sample_post_k, dim3(256), dim3(256), 0, stream,
                       YQ2, bq2, u_post, actions, XZ, out, t);
    if (t < 63) {
      // pre(t+1) -> PREY -> XPRE -> GX(t+1)
      GArg pre{XZ, 1040, XZ, 1040, 1030, W_pre, 1030, PREY, 1024, 1030};
      hipLaunchKernelGGL(gemm64_k, dim3(16, 4, 3), dim3(128), 0, stream, pre, pre, 3, 24);
      hipLaunchKernelGGL(lnsilu256_k, dim3(256), dim3(256), 0, stream,
                         PREY, 3, b_pre, g_pre, be_pre, XPRE);
      GArg gx{XPRE, 1024, XPRE, 1024, 1024, W_ih, 1024, GX, 3072, 1024};
      hipLaunchKernelGGL(gemm128_k, dim3(24, 2, 3), dim3(256), 0, stream, gx, gx, 3, 24);
    }
  }

  // ---- batched prior chain (value-safe), 4 chunks of 4096 hs-rows ----
  for (int bc = 0; bc < 4; ++bc) {
    const float* hsrc = out + (size_t)bc * 4096 * 1024;
    float* ppc = out + 2 * NOUT + (size_t)bc * 4096 * 1024;
    GArg y1{hsrc, 1024, hsrc, 1024, 1 << 30, Wp1, 1024, Y1c, 1024, 1024};
    hipLaunchKernelGGL(gemm128_k, dim3(8, 32, 1), dim3(256), 0, stream, y1, y1, 1, 64);
    hipLaunchKernelGGL(lnsilu256_k, dim3(4096), dim3(256), 0, stream,
                       Y1c, 1, bp1, gp, bpn, Y1c);     // in-place, thread-local
    GArg y2{Y1c, 1024, Y1c, 1024, 1 << 30, Wp2, 1024, ppc, 1024, 1024};
    hipLaunchKernelGGL(gemm128_k, dim3(8, 32, 1), dim3(256), 0, stream, y2, y2, 1, 64);
  }
  hipLaunchKernelGGL(prior_soft_k, dim3(16384), dim3(256), 0, stream,
                     out + 2 * NOUT, bp2);              // in-place softmax
}

// Round 10
// 11146.494 us; speedup vs baseline: 1.2301x; 1.2301x over previous
//
#include <hip/hip_runtime.h>
#include <hip/hip_bf16.h>
#include <math.h>

// RSSM scan — numpy-realization f32 (frozen numerics):
//   GEMM: OpenBLAS replica — K panels of 384 (24 BK=16 tiles), per-output
//   single-acc k-ascending fmaf chain per panel, panels folded ascending by
//   the consumer. Reductions: numpy pairwise replica. CR transcendentals.
// r10: revert to 64x64 tiles (CU coverage; r9's 128^2 starved at 144 blocks),
// float4 staging (content-identical LDS), prior chain folded into in-loop
// launches (rides idle z/y-slices; no post-loop tail), r9 elementwise kept.

struct GArg {
  const float* A0; int lda0;
  const float* A1; int lda1;
  int kSplit;
  const float* W; int ldw;
  float* C; int N; int K;             // panel s written at C + s*256*N
};

struct LArg {
  const float* Y; int S;              // fold S panels (stride 262144)
  const float* bias; const float* g; const float* be;
  float* O;
};

__device__ __forceinline__ float exp_cr(float x)  { return (float)exp((double)x); }
__device__ __forceinline__ float log_cr(float x)  { return (float)log((double)x); }
__device__ __forceinline__ float tanh_cr(float x) { return (float)tanh((double)x); }
__device__ __forceinline__ float sigmoid_cr(float x) {
  float e = exp_cr(-x);
  float d = __fadd_rn(1.0f, e);
  return __fdiv_rn(1.0f, d);
}

// ---- 64x64 tile, 256 threads, 4x4/thread, dbuf, 3-way z-slice select ----
__global__ __launch_bounds__(256) void gemm_k(GArg g0, GArg g1, GArg g2,
                                              int z1, int z2) {
  int z = blockIdx.z;
  GArg G; int s;
  if (z < z1)      { G = g0; s = z; }
  else if (z < z2) { G = g1; s = z - z1; }
  else             { G = g2; s = z - z2; }
  int n0 = blockIdx.x * 64;
  if (n0 >= G.N) return;
  int m0 = blockIdx.y * 64;

  __shared__ float As[2][16][68];   // [buf][k][m]; reads/writes <=2-way banks
  __shared__ float Bs[2][16][68];

  int tid = threadIdx.x;
  int tx = tid & 15, ty = tid >> 4;   // compute: cols tx*4, rows ty*4 (r8 map)
  int kq = tid & 3,  rr = tid >> 2;   // vec staging: k-quad, row 0..63

  bool vecOK = ((G.ldw & 3) == 0) && ((G.lda0 & 3) == 0) && ((G.lda1 & 3) == 0)
            && (((G.kSplit & 15) == 0) || (G.kSplit >= G.K));

  float acc[4][4];
  #pragma unroll
  for (int j = 0; j < 4; ++j)
    #pragma unroll
    for (int i = 0; i < 4; ++i) acc[j][i] = 0.0f;

  int nt = (G.K + 15) >> 4;
  int t0 = s * 24, t1 = min(nt, t0 + 24);

  float a[4], w[4];
  int useVec = 0;

  auto stage_load = [&](int kt) {
    int kb = kt * 16;
    useVec = vecOK && (kb + 16 <= G.K);
    if (useVec) {
      int k = kb + kq * 4;
      float4 av = (k < G.kSplit)
        ? *(const float4*)(G.A0 + (size_t)(m0 + rr) * G.lda0 + k)
        : *(const float4*)(G.A1 + (size_t)(m0 + rr) * G.lda1 + (k - G.kSplit));
      float4 wv = *(const float4*)(G.W + (size_t)(n0 + rr) * G.ldw + k);
      a[0] = av.x; a[1] = av.y; a[2] = av.z; a[3] = av.w;
      w[0] = wv.x; w[1] = wv.y; w[2] = wv.z; w[3] = wv.w;
    } else {
      int k = kb + tx;
      #pragma unroll
      for (int i = 0; i < 4; ++i) { a[i] = 0.0f; w[i] = 0.0f; }
      if (k < G.K) {
        if (k < G.kSplit) {
          const float* Ap = G.A0 + (size_t)(m0 + ty * 4) * G.lda0 + k;
          #pragma unroll
          for (int i = 0; i < 4; ++i) a[i] = Ap[(size_t)i * G.lda0];
        } else {
          const float* Ap = G.A1 + (size_t)(m0 + ty * 4) * G.lda1 + (k - G.kSplit);
          #pragma unroll
          for (int i = 0; i < 4; ++i) a[i] = Ap[(size_t)i * G.lda1];
        }
        const float* Wp = G.W + (size_t)(n0 + ty * 4) * G.ldw + k;
        #pragma unroll
        for (int i = 0; i < 4; ++i) w[i] = Wp[(size_t)i * G.ldw];
      }
    }
  };
  auto stage_write = [&](int b) {
    if (useVec) {
      #pragma unroll
      for (int i = 0; i < 4; ++i) {
        As[b][kq * 4 + i][rr] = a[i];    // bank (16kq+4i+rr)%32: 2-way, free
        Bs[b][kq * 4 + i][rr] = w[i];
      }
    } else {
      *(float4*)&As[b][tx][ty * 4] = make_float4(a[0], a[1], a[2], a[3]);
      *(float4*)&Bs[b][tx][ty * 4] = make_float4(w[0], w[1], w[2], w[3]);
    }
  };
  auto compute = [&](int b) {
    #pragma unroll
    for (int kk = 0; kk < 16; ++kk) {
      float4 av = *(const float4*)&As[b][kk][ty * 4];
      float4 bv = *(const float4*)&Bs[b][kk][tx * 4];
      float aa[4] = {av.x, av.y, av.z, av.w};
      float bb[4] = {bv.x, bv.y, bv.z, bv.w};
      #pragma unroll
      for (int j = 0; j < 4; ++j)
        #pragma unroll
        for (int i = 0; i < 4; ++i)
          acc[j][i] = fmaf(aa[j], bb[i], acc[j][i]);   // k-ascending chain
    }
  };

  stage_load(t0); stage_write(0); __syncthreads();
  int cur = 0;
  for (int kt = t0; kt < t1; ++kt) {
    if (kt + 1 < t1) {
      stage_load(kt + 1);
      compute(cur);
      stage_write(cur ^ 1);
      __syncthreads();
      cur ^= 1;
    } else compute(cur);
  }

  float* Cp = G.C + (size_t)s * 256 * G.N;
  #pragma unroll
  for (int j = 0; j < 4; ++j)
    *(float4*)&Cp[(size_t)(m0 + ty * 4 + j) * G.N + n0 + tx * 4] =
      make_float4(acc[j][0], acc[j][1], acc[j][2], acc[j][3]);
}

// ---- LN + SiLU, 256 thr/row, grid.y selects job; wave0 frozen reduction ----
__global__ __launch_bounds__(256) void lnsilu2_k(LArg l0, LArg l1) {
  LArg L = blockIdx.y ? l1 : l0;
  __shared__ float xs[64][20];
  __shared__ float stats[2];
  int row = blockIdx.x, tid = threadIdx.x;
  int cl = tid & 63, iq = tid >> 6;
  int kb = cl >> 3, j = cl & 7;

  float xv[4];
  #pragma unroll
  for (int q = 0; q < 4; ++q) {
    int i = iq * 4 + q;
    int n = kb * 128 + 8 * i + j;
    size_t idx = (size_t)row * 1024 + n;
    float x = L.Y[idx];
    for (int ss = 1; ss < L.S; ++ss) x = __fadd_rn(x, L.Y[(size_t)ss * 262144 + idx]);
    x = __fadd_rn(x, L.bias[n]);
    xv[q] = x;
    xs[cl][i] = x;
  }
  __syncthreads();
  if (tid < 64) {
    float r = xs[cl][0];
    #pragma unroll
    for (int i = 1; i < 16; ++i) r = __fadd_rn(r, xs[cl][i]);
    r = __fadd_rn(r, __shfl_xor(r, 1));
    r = __fadd_rn(r, __shfl_xor(r, 2));
    r = __fadd_rn(r, __shfl_xor(r, 4));
    r = __fadd_rn(r, __shfl_xor(r, 8));
    r = __fadd_rn(r, __shfl_xor(r, 16));
    r = __fadd_rn(r, __shfl_xor(r, 32));
    float mean = __fmul_rn(r, 0.0009765625f);
    float d0 = __fsub_rn(xs[cl][0], mean);
    float r2 = __fmul_rn(d0, d0);
    #pragma unroll
    for (int i = 1; i < 16; ++i) {
      float d = __fsub_rn(xs[cl][i], mean);
      r2 = __fadd_rn(r2, __fmul_rn(d, d));
    }
    r2 = __fadd_rn(r2, __shfl_xor(r2, 1));
    r2 = __fadd_rn(r2, __shfl_xor(r2, 2));
    r2 = __fadd_rn(r2, __shfl_xor(r2, 4));
    r2 = __fadd_rn(r2, __shfl_xor(r2, 8));
    r2 = __fadd_rn(r2, __shfl_xor(r2, 16));
    r2 = __fadd_rn(r2, __shfl_xor(r2, 32));
    float var = __fmul_rn(r2, 0.0009765625f);
    float sdv = __fsqrt_rn(__fadd_rn(var, (float)1e-5));
    if (cl == 0) { stats[0] = mean; stats[1] = __fdiv_rn(1.0f, sdv); }
  }
  __syncthreads();
  float mean = stats[0], rstd = stats[1];
  #pragma unroll
  for (int q = 0; q < 4; ++q) {
    int i = iq * 4 + q;
    int n = kb * 128 + 8 * i + j;
    float d = __fsub_rn(xv[q], mean);
    float t = __fmul_rn(__fmul_rn(d, rstd), L.g[n]);
    t = __fadd_rn(t, L.be[n]);
    L.O[(size_t)row * 1024 + n] = __fmul_rn(t, sigmoid_cr(t));   // silu
  }
}

// ---- GRU combine + LN, 256 thr/row; wave0 frozen reduction ----
__global__ __launch_bounds__(256) void gru256_k(
  const float* GX, const float* GH, float* H,
  const float* b_ih, const float* b_hh, const float* g_gn, const float* b_gn,
  float* out, int t)
{
  __shared__ float xs[64][20];
  __shared__ float stats[2];
  int row = blockIdx.x, tid = threadIdx.x;
  int cl = tid & 63, iq = tid >> 6;
  int kb = cl >> 3, j = cl & 7;

  float hv[4];
  #pragma unroll
  for (int q = 0; q < 4; ++q) {
    int i = iq * 4 + q;
    int n = kb * 128 + 8 * i + j;
    size_t i0 = (size_t)row * 3072 + n;
    #define FOLD3(P, off) __fadd_rn(__fadd_rn((P)[off], (P)[786432 + (off)]), (P)[1572864 + (off)])
    float xr = __fadd_rn(FOLD3(GX, i0),        b_ih[n]);
    float xu = __fadd_rn(FOLD3(GX, i0 + 1024), b_ih[n + 1024]);
    float xn = __fadd_rn(FOLD3(GX, i0 + 2048), b_ih[n + 2048]);
    float hr = __fadd_rn(FOLD3(GH, i0),        b_hh[n]);
    float hu = __fadd_rn(FOLD3(GH, i0 + 1024), b_hh[n + 1024]);
    float hn = __fadd_rn(FOLD3(GH, i0 + 2048), b_hh[n + 2048]);
    #undef FOLD3
    float r = sigmoid_cr(__fadd_rn(xr, hr));
    float u = sigmoid_cr(__fadd_rn(xu, hu));
    float nn = tanh_cr(__fadd_rn(xn, __fmul_rn(r, hn)));
    float h2 = __fadd_rn(__fmul_rn(__fsub_rn(1.0f, u), nn),
                         __fmul_rn(u, H[(size_t)row * 1024 + n]));
    hv[q] = h2;
    xs[cl][i] = h2;
  }
  __syncthreads();
  if (tid < 64) {
    float r = xs[cl][0];
    #pragma unroll
    for (int i = 1; i < 16; ++i) r = __fadd_rn(r, xs[cl][i]);
    r = __fadd_rn(r, __shfl_xor(r, 1));
    r = __fadd_rn(r, __shfl_xor(r, 2));
    r = __fadd_rn(r, __shfl_xor(r, 4));
    r = __fadd_rn(r, __shfl_xor(r, 8));
    r = __fadd_rn(r, __shfl_xor(r, 16));
    r = __fadd_rn(r, __shfl_xor(r, 32));
    float mean = __fmul_rn(r, 0.0009765625f);
    float d0 = __fsub_rn(xs[cl][0], mean);
    float r2 = __fmul_rn(d0, d0);
    #pragma unroll
    for (int i = 1; i < 16; ++i) {
      float d = __fsub_rn(xs[cl][i], mean);
      r2 = __fadd_rn(r2, __fmul_rn(d, d));
    }
    r2 = __fadd_rn(r2, __shfl_xor(r2, 1));
    r2 = __fadd_rn(r2, __shfl_xor(r2, 2));
    r2 = __fadd_rn(r2, __shfl_xor(r2, 4));
    r2 = __fadd_rn(r2, __shfl_xor(r2, 8));
    r2 = __fadd_rn(r2, __shfl_xor(r2, 16));
    r2 = __fadd_rn(r2, __shfl_xor(r2, 32));
    float var = __fmul_rn(r2, 0.0009765625f);
    float sdv = __fsqrt_rn(__fadd_rn(var, (float)1e-5));
    if (cl == 0) { stats[0] = mean; stats[1] = __fdiv_rn(1.0f, sdv); }
  }
  __syncthreads();
  float mean = stats[0], rstd = stats[1];
  #pragma unroll
  for (int q = 0; q < 4; ++q) {
    int i = iq * 4 + q;
    int n = kb * 128 + 8 * i + j;
    float d = __fsub_rn(hv[q], mean);
    float h3 = __fadd_rn(__fmul_rn(__fmul_rn(d, rstd), g_gn[n]), b_gn[n]);
    H[(size_t)row * 1024 + n] = h3;
    out[((size_t)row * 64 + t) * 1024 + n] = h3;
  }
}

// ---- y0: posterior softmax+unimix+gumbel argmax (FROZEN) -> qp/zs/carry
// ---- y1: prior fold3+softmax+unimix (value-safe) -> pp
__global__ __launch_bounds__(256) void sample2_k(
  const float* Yq, const float* bq2, const float* Y2p, const float* bp2,
  const float* u_post, const float* actions, float* XZ, float* out, int t)
{
  const size_t NOUT = 16777216ull;
  int b = blockIdx.x, tid = threadIdx.x;
  int d = tid >> 3, lane = tid & 7;
  const float C0 = (float)(1.0 - 0.01);
  const float C1 = (float)(0.01 / 32.0);
  int prior = blockIdx.y;
  const float* Y = prior ? Y2p : Yq;
  const float* bias = prior ? bp2 : bq2;

  float lg[4];
  #pragma unroll
  for (int i = 0; i < 4; ++i) {
    int col = d * 32 + lane + 8 * i;
    size_t idx = (size_t)b * 1024 + col;
    float x = __fadd_rn(__fadd_rn(Y[idx], Y[262144 + idx]), Y[524288 + idx]);
    lg[i] = __fadd_rn(x, bias[col]);
  }
  float mx = fmaxf(fmaxf(lg[0], lg[1]), fmaxf(lg[2], lg[3]));
  for (int off = 4; off; off >>= 1) mx = fmaxf(mx, __shfl_xor(mx, off, 8));

  float e[4];
  #pragma unroll
  for (int i = 0; i < 4; ++i) e[i] = exp_cr(__fsub_rn(lg[i], mx));
  float ssum = e[0];
  ssum = __fadd_rn(ssum, e[1]);
  ssum = __fadd_rn(ssum, e[2]);
  ssum = __fadd_rn(ssum, e[3]);
  ssum = __fadd_rn(ssum, __shfl_xor(ssum, 1, 8));
  ssum = __fadd_rn(ssum, __shfl_xor(ssum, 2, 8));
  ssum = __fadd_rn(ssum, __shfl_xor(ssum, 4, 8));

  float p[4];
  #pragma unroll
  for (int i = 0; i < 4; ++i) {
    float pr = __fdiv_rn(e[i], ssum);
    p[i] = __fadd_rn(__fmul_rn(C0, pr), C1);
  }

  size_t ob = ((size_t)b * 64 + t) * 1024;
  if (prior) {
    #pragma unroll
    for (int i = 0; i < 4; ++i)
      out[2 * NOUT + ob + (d * 32 + lane + 8 * i)] = p[i];
    return;
  }

  float bv = -3.4e38f; int bc = 33;
  #pragma unroll
  for (int i = 0; i < 4; ++i) {
    int c = lane + 8 * i, col = d * 32 + c;
    out[3 * NOUT + ob + col] = p[i];
    float uu = u_post[((size_t)t * 256 + b) * 1024 + col];
    float l1 = log_cr(uu);
    float v1 = -l1;
    float l2 = log_cr(v1);
    float gu = -l2;
    float lp = log_cr(p[i]);
    float val = __fadd_rn(lp, gu);
    if (val > bv) { bv = val; bc = c; }       // first max (c ascending)
  }
  for (int off = 4; off; off >>= 1) {
    float ov = __shfl_xor(bv, off, 8);
    int   oc = __shfl_xor(bc, off, 8);
    if (ov > bv || (ov == bv && oc < bc)) { bv = ov; bc = oc; }
  }
  #pragma unroll
  for (int i = 0; i < 4; ++i) {
    int c = lane + 8 * i, col = d * 32 + c;
    float zv = 0.0f;
    if (c == bc) zv = __fsub_rn(__fadd_rn(1.0f, p[i]), p[i]);
    out[NOUT + ob + col] = zv;
    XZ[(size_t)b * 1040 + col] = zv;
  }
  if (tid < 6 && (t + 1) < 64)
    XZ[(size_t)b * 1040 + 1024 + tid] = actions[((size_t)b * 64 + (t + 1)) * 6 + tid];
}

__global__ __launch_bounds__(256) void init_k(const float* h_init, const float* z_init,
                                              const float* actions, float* H, float* XZ)
{
  int b = blockIdx.x, tid = threadIdx.x;
  #pragma unroll
  for (int j = 0; j < 4; ++j) {
    int n = tid + j * 256;
    H [(size_t)b * 1024 + n] = h_init[(size_t)b * 1024 + n];
    XZ[(size_t)b * 1040 + n] = z_init[(size_t)b * 1024 + n];
  }
  if (tid < 6) XZ[(size_t)b * 1040 + 1024 + tid] = actions[(size_t)b * 64 * 6 + tid];
}

extern "C" void kernel_launch(void* const* d_in, const int* in_sizes, int n_in,
                              void* d_out, int out_size, void* d_ws, size_t ws_size,
                              hipStream_t stream)
{
  const float* embeds  = (const float*)d_in[0];
  const float* actions = (const float*)d_in[1];
  const float* h_init  = (const float*)d_in[2];
  const float* z_init  = (const float*)d_in[3];
  const float* W_pre   = (const float*)d_in[4];
  const float* b_pre   = (const float*)d_in[5];
  const float* g_pre   = (const float*)d_in[6];
  const float* be_pre  = (const float*)d_in[7];
  const float* W_ih    = (const float*)d_in[8];
  const float* W_hh    = (const float*)d_in[9];
  const float* b_ih    = (const float*)d_in[10];
  const float* b_hh    = (const float*)d_in[11];
  const float* g_gn    = (const float*)d_in[12];
  const float* b_gn    = (const float*)d_in[13];
  const float* Wp1     = (const float*)d_in[14];
  const float* bp1     = (const float*)d_in[15];
  const float* gp      = (const float*)d_in[16];
  const float* bpn     = (const float*)d_in[17];
  const float* Wp2     = (const float*)d_in[18];
  const float* bp2     = (const float*)d_in[19];
  const float* Wq1     = (const float*)d_in[20];
  const float* bq1     = (const float*)d_in[21];
  const float* gq      = (const float*)d_in[22];
  const float* bqn     = (const float*)d_in[23];
  const float* Wq2     = (const float*)d_in[24];
  const float* bq2     = (const float*)d_in[25];
  // d_in[26] = u_prior: unused
  const float* u_post  = (const float*)d_in[27];
  float* out           = (float*)d_out;
  const int KS = 1 << 30;   // "no split" sentinel (vec-safe)

  // workspace: 9,441,280 floats = 37.8 MB (lifetime-audited aliases)
  float* W0   = (float*)d_ws;
  float* H    = W0;                    // 262144
  float* XZ   = W0 + 262144;           // 266240 (row stride 1040)
  float* PREY = W0 + 528384;           // 786432 (3 panels); alias Q1A[262144]
  float* Q1A  = PREY;                  //   Q1A: wr L3, rd L4; PREY: wr L6, rd L7
  float* GX   = W0 + 1314816;          // 2359296 (3 panels)
  float* GH   = W0 + 3674112;          // 2359296 (3 panels; lives across step)
  float* YQ   = W0 + 6033408;          // 1572864 (6 panels); alias Y2p[786432]
  float* Y2p  = YQ;                    //   YQ: wr L2, rd L3; Y2p: wr L4, rd L5
  float* YQ2  = W0 + 7606272;          // 786432 (3 panels); alias XPRE[262144]
  float* XPRE = YQ2;                   //   YQ2: wr L4, rd L5; XPRE: wr L7, rd L8
  float* Y1p  = W0 + 8392704;          // 786432 (3 panels)
  float* P1Ap = W0 + 9179136;          // 262144

  hipLaunchKernelGGL(init_k, dim3(256), dim3(256), 0, stream, h_init, z_init, actions, H, XZ);

  // prefix: pre(0) -> ln -> GX(0)+GH(0)
  GArg pre0{XZ, 1040, XZ, 1040, KS, W_pre, 1030, PREY, 1024, 1030};
  hipLaunchKernelGGL(gemm_k, dim3(16, 4, 3), dim3(256), 0, stream, pre0, pre0, pre0, 3, 3);
  {
    LArg lp{PREY, 3, b_pre, g_pre, be_pre, XPRE};
    hipLaunchKernelGGL(lnsilu2_k, dim3(256, 1), dim3(256), 0, stream, lp, lp);
    GArg gx{XPRE, 1024, XPRE, 1024, KS, W_ih, 1024, GX, 3072, 1024};
    GArg gh{H,    1024, H,    1024, KS, W_hh, 1024, GH, 3072, 1024};
    hipLaunchKernelGGL(gemm_k, dim3(48, 4, 6), dim3(256), 0, stream, gx, gh, gh, 3, 6);
  }

  for (int t = 0; t < 64; ++t) {
    // L1: gru -> H(=hs[t]), out
    hipLaunchKernelGGL(gru256_k, dim3(256), dim3(256), 0, stream,
                       GX, GH, H, b_ih, b_hh, g_gn, b_gn, out, t);
    // L2: q1(t) [6] + GH(t+1) [3] + priorY1(t) [3]
    GArg q1 {H, 1024, embeds + (size_t)t * 1024, 65536, 1024, Wq1, 2048, YQ, 1024, 2048};
    GArg gh {H, 1024, H, 1024, KS, W_hh, 1024, GH, 3072, 1024};
    GArg py1{out + (size_t)t * 1024, 65536, out, 65536, KS, Wp1, 1024, Y1p, 1024, 1024};
    if (t < 63)
      hipLaunchKernelGGL(gemm_k, dim3(48, 4, 12), dim3(256), 0, stream, q1, gh, py1, 6, 9);
    else
      hipLaunchKernelGGL(gemm_k, dim3(48, 4, 9), dim3(256), 0, stream, q1, q1, py1, 6, 6);
    // L3: lnq -> Q1A ; priorLN -> P1Ap
    {
      LArg lq{YQ, 6, bq1, gq, bqn, Q1A};
      LArg lr{Y1p, 3, bp1, gp, bpn, P1Ap};
      hipLaunchKernelGGL(lnsilu2_k, dim3(256, 2), dim3(256), 0, stream, lq, lr);
    }
    // L4: q2(t) [3] + priorY2(t) [3]
    GArg q2 {Q1A,  1024, Q1A,  1024, KS, Wq2, 1024, YQ2, 1024, 1024};
    GArg py2{P1Ap, 1024, P1Ap, 1024, KS, Wp2, 1024, Y2p, 1024, 1024};
    hipLaunchKernelGGL(gemm_k, dim3(16, 4, 6), dim3(256), 0, stream, q2, q2, py2, 3, 3);
    // L5: posterior sample (y0) + prior softmax (y1)
    hipLaunchKernelGGL(sample2_k, dim3(256, 2), dim3(256), 0, stream,
                       YQ2, bq2, Y2p, bp2, u_post, actions, XZ, out, t);
    if (t < 63) {
      // L6: pre(t+1)  (K=1030: scalar staging path)
      GArg pre{XZ, 1040, XZ, 1040, KS, W_pre, 1030, PREY, 1024, 1030};
      hipLaunchKernelGGL(gemm_k, dim3(16, 4, 3), dim3(256), 0, stream, pre, pre, pre, 3, 3);
      // L7: ln-pre -> XPRE
      LArg lp{PREY, 3, b_pre, g_pre, be_pre, XPRE};
      hipLaunchKernelGGL(lnsilu2_k, dim3(256, 1), dim3(256), 0, stream, lp, lp);
      // L8: GX(t+1)
      GArg gx{XPRE, 1024, XPRE, 1024, KS, W_ih, 1024, GX, 3072, 1024};
      hipLaunchKernelGGL(gemm_k, dim3(48, 4, 3), dim3(256), 0, stream, gx, gx, gx, 3, 3);
    }
  }
}